// Round 2
// baseline (362.362 us; speedup 1.0000x reference)
//
#include <hip/hip_runtime.h>
#include <stdint.h>

// AtomicDifferentiatedDense: gated per-token dense layer.
// out[t,:] = relu(x[t,:] @ W[e(t)] + b[e(t)]) where e(t) = index of
// atom_numbers[t] in atom_cases, else 0.
// B=2048, A=128 -> T=262144 tokens; K=CI=128, N=CO=128, E=4.
//
// Strategy R1 (resubmit after infra timeout): compute all 4 experts with
// bf16 MFMA (16x16x32), select per row in epilogue. W staged once per
// persistent block into LDS in MFMA B-fragment layout (128 KB).
// A-fragments loaded direct from global, predicated on row activity
// (saves ~74 MB of x reads). Memory-bound; floor ~31 us, predict 40-60 us.

typedef __attribute__((ext_vector_type(8))) short short8;
typedef __attribute__((ext_vector_type(4))) float f32x4;

__device__ __forceinline__ unsigned short f2bf(float f) {
    union { float f; uint32_t u; } v; v.f = f;
    uint32_t u = v.u;
    return (unsigned short)((u + 0x7FFFu + ((u >> 16) & 1u)) >> 16);  // RNE
}

// tokens = 262144, tile = 128 rows -> 2048 tiles; grid=256 persistent blocks.
__global__ __launch_bounds__(512, 2) void atomic_dense_kernel(
    const float* __restrict__ x,
    const int*   __restrict__ atom_numbers,
    const float* __restrict__ W,
    const float* __restrict__ bvec,
    const int*   __restrict__ cases,
    float*       __restrict__ out)
{
    // B-fragment layout LDS: 4 experts x 4 ksteps x 8 ntiles fragments,
    // each fragment = 64 lanes x 8 bf16 (16B/lane). Total 128 KB.
    __shared__ unsigned short Wlds[65536];

    const int tid = threadIdx.x;

    // ---- stage W -> LDS in fragment layout (once per block) ----
    for (int idx = tid; idx < 65536; idx += 512) {
        const int col = idx & 15;          // n within tile (0..15)
        const int j   = (idx >> 4) & 7;    // element within fragment
        const int g   = (idx >> 7) & 3;    // lane group (k group)
        const int n   = (idx >> 9) & 7;    // n tile
        const int kk  = (idx >> 12) & 3;   // k step
        const int e   = (idx >> 14) & 3;   // expert
        const int k = kk * 32 + g * 8 + j;
        const float w = W[(size_t)(e * 128 + k) * 128 + n * 16 + col];
        const int fragid = (e * 4 + kk) * 8 + n;
        const int lane = g * 16 + col;
        Wlds[fragid * 512 + lane * 8 + j] = f2bf(w);
    }
    __syncthreads();

    const int lane = tid & 63;
    const int wv   = tid >> 6;   // 0..7
    const int g    = lane >> 4;  // 0..3
    const int c16  = lane & 15;
    const int rg   = wv >> 2;    // 0..1 : which 64-row half of the tile
    const int ng   = wv & 3;     // 0..3 : which pair of 16-col tiles

    const int c0 = cases[0], c1 = cases[1], c2 = cases[2], c3 = cases[3];

    // bias values for this lane's two columns, all experts (hoisted)
    float bv[4][2];
    #pragma unroll
    for (int e = 0; e < 4; ++e)
        #pragma unroll
        for (int n = 0; n < 2; ++n)
            bv[e][n] = bvec[e * 128 + (ng * 2 + n) * 16 + c16];

    const short8* __restrict__ Wfrag = (const short8*)Wlds;

    for (int t = blockIdx.x; t < 2048; t += gridDim.x) {
        const int tokbase = t * 128 + rg * 64;

        // expert id for this lane's A-row in each of the 4 M-fragments
        int eA[4];
        #pragma unroll
        for (int mf = 0; mf < 4; ++mf) {
            const int an = atom_numbers[tokbase + mf * 16 + c16];
            eA[mf] = (an == c0) ? 0 : (an == c1) ? 1 : (an == c2) ? 2
                   : (an == c3) ? 3 : -1;
        }

        f32x4 acc[4][4][2];  // [expert][mfrag][ntile]
        #pragma unroll
        for (int e = 0; e < 4; ++e)
            #pragma unroll
            for (int mf = 0; mf < 4; ++mf)
                #pragma unroll
                for (int n = 0; n < 2; ++n)
                    acc[e][mf][n] = (f32x4){0.f, 0.f, 0.f, 0.f};

        #pragma unroll
        for (int kk = 0; kk < 4; ++kk) {
            // A fragments for this k-step (predicated load: skip dead rows)
            short8 afr[4];
            #pragma unroll
            for (int mf = 0; mf < 4; ++mf) {
                float4 fa = make_float4(0.f, 0.f, 0.f, 0.f);
                float4 fb = make_float4(0.f, 0.f, 0.f, 0.f);
                if (eA[mf] >= 0) {
                    const float* base = x
                        + (size_t)(tokbase + mf * 16 + c16) * 128
                        + kk * 32 + g * 8;
                    fa = *(const float4*)base;
                    fb = *(const float4*)(base + 4);
                }
                short8 a;
                a[0] = (short)f2bf(fa.x); a[1] = (short)f2bf(fa.y);
                a[2] = (short)f2bf(fa.z); a[3] = (short)f2bf(fa.w);
                a[4] = (short)f2bf(fb.x); a[5] = (short)f2bf(fb.y);
                a[6] = (short)f2bf(fb.z); a[7] = (short)f2bf(fb.w);
                afr[mf] = a;
            }
            #pragma unroll
            for (int e = 0; e < 4; ++e) {
                const short8 b0 = Wfrag[((e * 4 + kk) * 8 + ng * 2 + 0) * 64 + lane];
                const short8 b1 = Wfrag[((e * 4 + kk) * 8 + ng * 2 + 1) * 64 + lane];
                #pragma unroll
                for (int mf = 0; mf < 4; ++mf) {
                    acc[e][mf][0] = __builtin_amdgcn_mfma_f32_16x16x32_bf16(
                        afr[mf], b0, acc[e][mf][0], 0, 0, 0);
                    acc[e][mf][1] = __builtin_amdgcn_mfma_f32_16x16x32_bf16(
                        afr[mf], b1, acc[e][mf][1], 0, 0, 0);
                }
            }
        }

        // ---- epilogue: per-row expert select, +b, relu, store ----
        #pragma unroll
        for (int mf = 0; mf < 4; ++mf) {
            const int rowb = tokbase + mf * 16 + g * 4;  // D rows: (l>>4)*4+r
            #pragma unroll
            for (int r = 0; r < 4; ++r) {
                const int an = atom_numbers[rowb + r];
                const int eid = (an == c0) ? 0 : (an == c1) ? 1
                              : (an == c2) ? 2 : (an == c3) ? 3 : -1;
                #pragma unroll
                for (int n = 0; n < 2; ++n) {
                    float v  = acc[0][mf][n][r];
                    float bb = bv[0][n];
                    v  = (eid == 1) ? acc[1][mf][n][r] : v;
                    bb = (eid == 1) ? bv[1][n] : bb;
                    v  = (eid == 2) ? acc[2][mf][n][r] : v;
                    bb = (eid == 2) ? bv[2][n] : bb;
                    v  = (eid == 3) ? acc[3][mf][n][r] : v;
                    bb = (eid == 3) ? bv[3][n] : bb;
                    const float res = (eid < 0) ? 0.f : fmaxf(v + bb, 0.f);
                    out[(size_t)(rowb + r) * 128 + (ng * 2 + n) * 16 + c16] = res;
                }
            }
        }
    }
}

extern "C" void kernel_launch(void* const* d_in, const int* in_sizes, int n_in,
                              void* d_out, int out_size, void* d_ws, size_t ws_size,
                              hipStream_t stream) {
    const float* x     = (const float*)d_in[0];
    const int*   an    = (const int*)d_in[1];
    const float* W     = (const float*)d_in[2];
    const float* bvec  = (const float*)d_in[3];
    const int*   cases = (const int*)d_in[4];
    float* out = (float*)d_out;

    dim3 grid(256), block(512);
    atomic_dense_kernel<<<grid, block, 0, stream>>>(x, an, W, bvec, cases, out);
}

// Round 3
// 259.652 us; speedup vs baseline: 1.3956x; 1.3956x over previous
//
#include <hip/hip_runtime.h>
#include <hip/hip_bf16.h>
#include <stdint.h>

// AtomicDifferentiatedDense: out[t,:] = relu(x[t,:] @ W[e(t)] + b[e(t)]), 0 if no match.
// T=262144 rows, K=N=128, E=4 experts (+1 "inactive" bucket).
//
// R2: expert compaction. 5 launches on one stream:
//  k0 zero counters | k1 histogram | k2 prefix | k3 scatter row indices
//  k4 GEMM: each block = 128 compacted rows of ONE expert (32KB LDS W-frags,
//     32-VGPR acc) or zero-fills 128 inactive rows.
// Attacks R1's diagnosis: occupancy 22%->~60%, no 4x redundant MFMA, no
// epilogue selects, no divergent loads.
//
// ws layout (uint32): [0..4]=cnt  [5..9]=base  [10..14]=cursor  [16..]=perm[262144]

typedef __attribute__((ext_vector_type(8))) short short8;
typedef __attribute__((ext_vector_type(4))) float f32x4;

#define NROWS 262144
#define PERM_OFF 16

__device__ __forceinline__ unsigned short f2bf(float f) {
    union { float f; uint32_t u; } v; v.f = f;
    uint32_t u = v.u;
    return (unsigned short)((u + 0x7FFFu + ((u >> 16) & 1u)) >> 16);  // RNE
}

__global__ void k0_zero(uint32_t* __restrict__ ws) {
    if (threadIdx.x < 16) ws[threadIdx.x] = 0u;
}

__device__ __forceinline__ int bucket_of(int v, int c0, int c1, int c2, int c3) {
    return (v == c0) ? 0 : (v == c1) ? 1 : (v == c2) ? 2 : (v == c3) ? 3 : 4;
}

// grid 256 x 256 threads, 4 rows/thread
__global__ __launch_bounds__(256) void k1_count(const int* __restrict__ an,
                                                const int* __restrict__ cases,
                                                uint32_t* __restrict__ ws) {
    __shared__ uint32_t lc[5];
    if (threadIdx.x < 5) lc[threadIdx.x] = 0u;
    __syncthreads();
    const int c0 = cases[0], c1 = cases[1], c2 = cases[2], c3 = cases[3];
    const int r0 = (blockIdx.x * 256 + threadIdx.x) * 4;
    const int4 a = *(const int4*)(an + r0);
    atomicAdd(&lc[bucket_of(a.x, c0, c1, c2, c3)], 1u);
    atomicAdd(&lc[bucket_of(a.y, c0, c1, c2, c3)], 1u);
    atomicAdd(&lc[bucket_of(a.z, c0, c1, c2, c3)], 1u);
    atomicAdd(&lc[bucket_of(a.w, c0, c1, c2, c3)], 1u);
    __syncthreads();
    if (threadIdx.x < 5) atomicAdd(&ws[threadIdx.x], lc[threadIdx.x]);
}

__global__ void k2_prefix(uint32_t* __restrict__ ws) {
    if (threadIdx.x == 0) {
        uint32_t run = 0;
        #pragma unroll
        for (int b = 0; b < 5; ++b) {
            ws[5 + b]  = run;   // base
            ws[10 + b] = run;   // cursor
            run += ws[b];
        }
    }
}

// grid 256 x 256 threads, 4 rows/thread; block-aggregated scatter
__global__ __launch_bounds__(256) void k3_scatter(const int* __restrict__ an,
                                                  const int* __restrict__ cases,
                                                  uint32_t* __restrict__ ws) {
    __shared__ uint32_t lc[5];     // per-block slot cursors (and final counts)
    __shared__ uint32_t lbase[5];  // block's base within each bucket
    if (threadIdx.x < 5) lc[threadIdx.x] = 0u;
    __syncthreads();
    const int c0 = cases[0], c1 = cases[1], c2 = cases[2], c3 = cases[3];
    const int r0 = (blockIdx.x * 256 + threadIdx.x) * 4;
    const int4 a = *(const int4*)(an + r0);
    int bk[4];
    bk[0] = bucket_of(a.x, c0, c1, c2, c3);
    bk[1] = bucket_of(a.y, c0, c1, c2, c3);
    bk[2] = bucket_of(a.z, c0, c1, c2, c3);
    bk[3] = bucket_of(a.w, c0, c1, c2, c3);
    uint32_t slot[4];
    #pragma unroll
    for (int i = 0; i < 4; ++i) slot[i] = atomicAdd(&lc[bk[i]], 1u);
    __syncthreads();
    if (threadIdx.x < 5) lbase[threadIdx.x] = atomicAdd(&ws[10 + threadIdx.x], lc[threadIdx.x]);
    __syncthreads();
    uint32_t* __restrict__ perm = ws + PERM_OFF;
    #pragma unroll
    for (int i = 0; i < 4; ++i) perm[lbase[bk[i]] + slot[i]] = (uint32_t)(r0 + i);
}

// grid 2053 x 512 threads. Block -> (bucket, chunk of 128 rows).
__global__ __launch_bounds__(512, 4) void k4_gemm(const float* __restrict__ x,
                                                  const float* __restrict__ W,
                                                  const float* __restrict__ bvec,
                                                  const uint32_t* __restrict__ ws,
                                                  float* __restrict__ out) {
    __shared__ unsigned short Wlds[16384];  // 32 KB: frag[kk*8+nt][lane][j]
    __shared__ int ridx[128];

    // map flat block id -> (bucket b, chunk)
    int b = -1, chunk = 0, accb = 0;
    #pragma unroll
    for (int bb = 0; bb < 5; ++bb) {
        const int nb = (int)((ws[bb] + 127u) >> 7);
        if (b < 0 && (int)blockIdx.x < accb + nb) { b = bb; chunk = blockIdx.x - accb; }
        accb += nb;
    }
    if (b < 0) return;

    const int cb   = (int)ws[b];
    const int rbeg = chunk << 7;
    const int nval = min(128, cb - rbeg);
    const uint32_t* __restrict__ perm = ws + PERM_OFF;
    if (threadIdx.x < 128)
        ridx[threadIdx.x] = (threadIdx.x < nval)
                          ? (int)perm[ws[5 + b] + rbeg + threadIdx.x] : -1;

    const int lane = threadIdx.x & 63;
    const int wv   = threadIdx.x >> 6;

    if (b == 4) {  // inactive rows -> zero-fill (full-line float4 stores)
        __syncthreads();
        const int half = lane >> 5;      // 0/1: which row of the pair
        const int l32  = lane & 31;      // float4 column slot
        const float4 z = make_float4(0.f, 0.f, 0.f, 0.f);
        #pragma unroll
        for (int it = 0; it < 8; ++it) {
            const int r = ridx[wv * 16 + it * 2 + half];
            if (r >= 0) *(float4*)(out + (size_t)r * 128 + l32 * 4) = z;
        }
        return;
    }

    // stage W[expert b] -> LDS in MFMA B-fragment layout (bf16)
    for (int idx = threadIdx.x; idx < 16384; idx += 512) {
        const int col = idx & 15;
        const int j   = (idx >> 4) & 7;
        const int gg  = (idx >> 7) & 3;
        const int nt  = (idx >> 9) & 7;
        const int kk  = (idx >> 12) & 3;
        const int k   = kk * 32 + gg * 8 + j;
        const float w = W[(size_t)(b * 128 + k) * 128 + nt * 16 + col];
        Wlds[((kk * 8 + nt) * 64 + gg * 16 + col) * 8 + j] = f2bf(w);
    }
    __syncthreads();

    const int g4  = lane >> 4;
    const int c16 = lane & 15;
    const int rg  = wv >> 2;   // 0..1: 64-row half
    const int ng  = wv & 3;    // 0..3: pair of 16-col tiles

    const float bv0 = bvec[b * 128 + (ng * 2 + 0) * 16 + c16];
    const float bv1 = bvec[b * 128 + (ng * 2 + 1) * 16 + c16];

    int arow[4];
    #pragma unroll
    for (int mf = 0; mf < 4; ++mf) arow[mf] = ridx[rg * 64 + mf * 16 + c16];

    f32x4 acc[4][2];
    #pragma unroll
    for (int mf = 0; mf < 4; ++mf) {
        acc[mf][0] = (f32x4){0.f, 0.f, 0.f, 0.f};
        acc[mf][1] = (f32x4){0.f, 0.f, 0.f, 0.f};
    }

    const short8* __restrict__ Wfrag = (const short8*)Wlds;

    #pragma unroll
    for (int kk = 0; kk < 4; ++kk) {
        short8 afr[4];
        #pragma unroll
        for (int mf = 0; mf < 4; ++mf) {
            float4 fa = make_float4(0.f, 0.f, 0.f, 0.f);
            float4 fb = make_float4(0.f, 0.f, 0.f, 0.f);
            if (arow[mf] >= 0) {
                const float* p = x + (size_t)arow[mf] * 128 + kk * 32 + g4 * 8;
                fa = *(const float4*)p;
                fb = *(const float4*)(p + 4);
            }
            short8 a;
            a[0] = (short)f2bf(fa.x); a[1] = (short)f2bf(fa.y);
            a[2] = (short)f2bf(fa.z); a[3] = (short)f2bf(fa.w);
            a[4] = (short)f2bf(fb.x); a[5] = (short)f2bf(fb.y);
            a[6] = (short)f2bf(fb.z); a[7] = (short)f2bf(fb.w);
            afr[mf] = a;
        }
        const short8 b0 = Wfrag[(kk * 8 + ng * 2 + 0) * 64 + lane];
        const short8 b1 = Wfrag[(kk * 8 + ng * 2 + 1) * 64 + lane];
        #pragma unroll
        for (int mf = 0; mf < 4; ++mf) {
            acc[mf][0] = __builtin_amdgcn_mfma_f32_16x16x32_bf16(afr[mf], b0, acc[mf][0], 0, 0, 0);
            acc[mf][1] = __builtin_amdgcn_mfma_f32_16x16x32_bf16(afr[mf], b1, acc[mf][1], 0, 0, 0);
        }
    }

    // epilogue: +bias, relu, store (D row = (lane>>4)*4 + r within 16-tile)
    #pragma unroll
    for (int mf = 0; mf < 4; ++mf) {
        #pragma unroll
        for (int r = 0; r < 4; ++r) {
            const int orow = ridx[rg * 64 + mf * 16 + g4 * 4 + r];
            if (orow >= 0) {
                out[(size_t)orow * 128 + (ng * 2 + 0) * 16 + c16] = fmaxf(acc[mf][0][r] + bv0, 0.f);
                out[(size_t)orow * 128 + (ng * 2 + 1) * 16 + c16] = fmaxf(acc[mf][1][r] + bv1, 0.f);
            }
        }
    }
}

extern "C" void kernel_launch(void* const* d_in, const int* in_sizes, int n_in,
                              void* d_out, int out_size, void* d_ws, size_t ws_size,
                              hipStream_t stream) {
    const float* x     = (const float*)d_in[0];
    const int*   an    = (const int*)d_in[1];
    const float* W     = (const float*)d_in[2];
    const float* bvec  = (const float*)d_in[3];
    const int*   cases = (const int*)d_in[4];
    float*    out = (float*)d_out;
    uint32_t* ws  = (uint32_t*)d_ws;

    k0_zero   <<<1,    64,  0, stream>>>(ws);
    k1_count  <<<256,  256, 0, stream>>>(an, cases, ws);
    k2_prefix <<<1,    64,  0, stream>>>(ws);
    k3_scatter<<<256,  256, 0, stream>>>(an, cases, ws);
    k4_gemm   <<<2053, 512, 0, stream>>>(x, W, bvec, ws, out);
}

// Round 4
// 242.683 us; speedup vs baseline: 1.4932x; 1.0699x over previous
//
#include <hip/hip_runtime.h>
#include <hip/hip_bf16.h>
#include <stdint.h>

// AtomicDifferentiatedDense: out[t,:] = relu(x[t,:] @ W[e(t)] + b[e(t)]), 0 if no match.
// T=262144 rows, K=N=128, E=4 experts (+1 inactive bucket).
//
// R3: 3 launches.
//  k_prep:    W -> bf16 MFMA B-fragment layout in ws (L2-resident); zero counters.
//  k_scatter: bucket rows into 5 fixed-capacity perm regions (block-aggregated atomics).
//  k_gemm:    block = 128 rows of one bucket. B-frags straight from L2 (no W LDS,
//             no staging barrier). A converted via v_cvt_pk_bf16_f32. Epilogue
//             transposes acc through LDS and stores full 512B row segments
//             (kills write-allocate fetch on out). Bucket 4 = zero-fill rows.
//
// ws layout: [u32 0..4] bucket counters | byte 1024: 128KB W-frags (bf16)
//            | byte 262144: perm, 5 regions x 262144 u32.

typedef __attribute__((ext_vector_type(8))) short short8;
typedef __attribute__((ext_vector_type(4))) float f32x4;

#define PERM_U32_OFF 65536
#define BUCKET_CAP   262144
#define OST_STRIDE   132    // floats; 528B row stride: 16B-aligned, bank-spread

union U16 { uint4 u; short8 s; };

__device__ __forceinline__ int bucket_of(int v, int c0, int c1, int c2, int c3) {
    return (v == c0) ? 0 : (v == c1) ? 1 : (v == c2) ? 2 : (v == c3) ? 3 : 4;
}

__device__ __forceinline__ uint32_t pkbf(float lo, float hi) {
    __hip_bfloat162 h = __float22bfloat162_rn(make_float2(lo, hi));
    uint32_t r;
    __builtin_memcpy(&r, &h, 4);
    return r;
}

// ---- k_prep: 32 blocks x 256 threads. W (4x128x128 f32) -> bf16 fragments. ----
__global__ __launch_bounds__(256) void k_prep(const float* __restrict__ W,
                                              uint32_t* __restrict__ ws) {
    if (blockIdx.x == 0 && threadIdx.x < 8) ws[threadIdx.x] = 0u;
    const int T   = blockIdx.x * 256 + threadIdx.x;     // 8192 threads
    const int c16 = T & 15;
    const int g   = (T >> 4) & 3;
    const int nt  = (T >> 6) & 7;
    const int kk  = (T >> 9) & 3;
    const int e   = (T >> 11) & 3;
    float v[8];
    #pragma unroll
    for (int j = 0; j < 8; ++j)
        v[j] = W[(size_t)(e * 128 + kk * 32 + g * 8 + j) * 128 + nt * 16 + c16];
    uint4 pack = make_uint4(pkbf(v[0], v[1]), pkbf(v[2], v[3]),
                            pkbf(v[4], v[5]), pkbf(v[6], v[7]));
    const int lane = g * 16 + c16;
    *(uint4*)((char*)ws + 1024 + e * 32768 + ((kk * 8 + nt) * 64 + lane) * 16) = pack;
}

// ---- k_scatter: 256 blocks x 256 threads, 4 rows/thread. ----
__global__ __launch_bounds__(256) void k_scatter(const int* __restrict__ an,
                                                 const int* __restrict__ cases,
                                                 uint32_t* __restrict__ ws) {
    __shared__ uint32_t lc[5], lbase[5];
    if (threadIdx.x < 5) lc[threadIdx.x] = 0u;
    __syncthreads();
    const int c0 = cases[0], c1 = cases[1], c2 = cases[2], c3 = cases[3];
    const int r0 = (blockIdx.x * 256 + threadIdx.x) * 4;
    const int4 a = *(const int4*)(an + r0);
    int bk[4];
    bk[0] = bucket_of(a.x, c0, c1, c2, c3);
    bk[1] = bucket_of(a.y, c0, c1, c2, c3);
    bk[2] = bucket_of(a.z, c0, c1, c2, c3);
    bk[3] = bucket_of(a.w, c0, c1, c2, c3);
    uint32_t slot[4];
    #pragma unroll
    for (int i = 0; i < 4; ++i) slot[i] = atomicAdd(&lc[bk[i]], 1u);
    __syncthreads();
    if (threadIdx.x < 5) lbase[threadIdx.x] = atomicAdd(&ws[threadIdx.x], lc[threadIdx.x]);
    __syncthreads();
    uint32_t* __restrict__ perm = ws + PERM_U32_OFF;
    #pragma unroll
    for (int i = 0; i < 4; ++i)
        perm[bk[i] * BUCKET_CAP + lbase[bk[i]] + slot[i]] = (uint32_t)(r0 + i);
}

// ---- k_gemm: 2052 blocks x 512 threads. ----
__global__ __launch_bounds__(512, 4) void k_gemm(const float* __restrict__ x,
                                                 const float* __restrict__ bvec,
                                                 const uint32_t* __restrict__ ws,
                                                 float* __restrict__ out) {
    __shared__ int   ridx[128];
    __shared__ float ost[128 * OST_STRIDE];   // 67584 B out-transpose staging

    // flat block id -> (bucket b, chunk)
    int b = -1, chunk = 0, accb = 0;
    #pragma unroll
    for (int bb = 0; bb < 5; ++bb) {
        const int nb = (int)((ws[bb] + 127u) >> 7);
        if (b < 0 && (int)blockIdx.x < accb + nb) { b = bb; chunk = blockIdx.x - accb; }
        accb += nb;
    }
    if (b < 0) return;

    const int cb   = (int)ws[b];
    const int rbeg = chunk << 7;
    const int nval = min(128, cb - rbeg);
    const uint32_t* __restrict__ perm = ws + PERM_U32_OFF + (size_t)b * BUCKET_CAP;
    if (threadIdx.x < 128)
        ridx[threadIdx.x] = (threadIdx.x < nval) ? (int)perm[rbeg + threadIdx.x] : -1;
    __syncthreads();

    const int lane = threadIdx.x & 63;
    const int wv   = threadIdx.x >> 6;

    if (b == 4) {  // inactive rows -> zeros, full 512B rows per wave pass
        const int half = lane >> 5, l32 = lane & 31;
        const float4 z = make_float4(0.f, 0.f, 0.f, 0.f);
        #pragma unroll
        for (int it = 0; it < 8; ++it) {
            const int r = ridx[wv * 16 + it * 2 + half];
            if (r >= 0) *(float4*)(out + (size_t)r * 128 + l32 * 4) = z;
        }
        return;
    }

    const int g4  = lane >> 4;
    const int c16 = lane & 15;
    const int rg  = wv >> 2;   // 0..1: 64-row half
    const int ng  = wv & 3;    // 0..3: pair of 16-col tiles

    const float bv0 = bvec[b * 128 + (ng * 2 + 0) * 16 + c16];
    const float bv1 = bvec[b * 128 + (ng * 2 + 1) * 16 + c16];

    int arow[4];
    #pragma unroll
    for (int mf = 0; mf < 4; ++mf) arow[mf] = ridx[rg * 64 + mf * 16 + c16];

    f32x4 acc[4][2];
    #pragma unroll
    for (int mf = 0; mf < 4; ++mf) {
        acc[mf][0] = (f32x4){0.f, 0.f, 0.f, 0.f};
        acc[mf][1] = (f32x4){0.f, 0.f, 0.f, 0.f};
    }

    const uint4* __restrict__ wf = (const uint4*)((const char*)ws + 1024 + b * 32768);

    #pragma unroll
    for (int kk = 0; kk < 4; ++kk) {
        U16 wb0, wb1;
        wb0.u = wf[(kk * 8 + ng * 2 + 0) * 64 + lane];
        wb1.u = wf[(kk * 8 + ng * 2 + 1) * 64 + lane];
        short8 afr[4];
        #pragma unroll
        for (int mf = 0; mf < 4; ++mf) {
            float4 fa = make_float4(0.f, 0.f, 0.f, 0.f);
            float4 fb = make_float4(0.f, 0.f, 0.f, 0.f);
            if (arow[mf] >= 0) {
                const float* p = x + (size_t)arow[mf] * 128 + kk * 32 + g4 * 8;
                fa = *(const float4*)p;
                fb = *(const float4*)(p + 4);
            }
            U16 av;
            av.u = make_uint4(pkbf(fa.x, fa.y), pkbf(fa.z, fa.w),
                              pkbf(fb.x, fb.y), pkbf(fb.z, fb.w));
            afr[mf] = av.s;
        }
        #pragma unroll
        for (int mf = 0; mf < 4; ++mf) {
            acc[mf][0] = __builtin_amdgcn_mfma_f32_16x16x32_bf16(afr[mf], wb0.s, acc[mf][0], 0, 0, 0);
            acc[mf][1] = __builtin_amdgcn_mfma_f32_16x16x32_bf16(afr[mf], wb1.s, acc[mf][1], 0, 0, 0);
        }
    }

    // epilogue: bias+relu into LDS (transpose), then full-row 16B stores
    #pragma unroll
    for (int mf = 0; mf < 4; ++mf) {
        #pragma unroll
        for (int r = 0; r < 4; ++r) {
            const int row = rg * 64 + mf * 16 + g4 * 4 + r;
            ost[row * OST_STRIDE + (ng * 2 + 0) * 16 + c16] = fmaxf(acc[mf][0][r] + bv0, 0.f);
            ost[row * OST_STRIDE + (ng * 2 + 1) * 16 + c16] = fmaxf(acc[mf][1][r] + bv1, 0.f);
        }
    }
    __syncthreads();

    const int l32 = lane & 31, lh = lane >> 5;
    #pragma unroll
    for (int i = 0; i < 8; ++i) {
        const int row  = wv * 16 + i * 2 + lh;
        const int orow = ridx[row];
        if (orow >= 0) {
            const float4 vv = *(const float4*)&ost[row * OST_STRIDE + l32 * 4];
            *(float4*)(out + (size_t)orow * 128 + l32 * 4) = vv;
        }
    }
}

extern "C" void kernel_launch(void* const* d_in, const int* in_sizes, int n_in,
                              void* d_out, int out_size, void* d_ws, size_t ws_size,
                              hipStream_t stream) {
    const float* x     = (const float*)d_in[0];
    const int*   an    = (const int*)d_in[1];
    const float* W     = (const float*)d_in[2];
    const float* bvec  = (const float*)d_in[3];
    const int*   cases = (const int*)d_in[4];
    float*    out = (float*)d_out;
    uint32_t* ws  = (uint32_t*)d_ws;

    k_prep   <<<32,   256, 0, stream>>>(W, ws);
    k_scatter<<<256,  256, 0, stream>>>(an, cases, ws);
    k_gemm   <<<2052, 512, 0, stream>>>(x, bvec, ws, out);
}